// Round 1
// baseline (496.893 us; speedup 1.0000x reference)
//
#include <hip/hip_runtime.h>
#include <cstdint>

// ---------- types ----------
typedef __attribute__((ext_vector_type(8))) __bf16  bf8v;   // MFMA A/B operand (4 VGPRs)
typedef __attribute__((ext_vector_type(4))) float   f4v;    // MFMA C/D
typedef __attribute__((ext_vector_type(8))) unsigned short ush8; // 16B staging chunk

__device__ __forceinline__ float bf2f(unsigned short u) {
    union { unsigned u; float f; } v; v.u = ((unsigned)u) << 16; return v.f;
}
__device__ __forceinline__ unsigned short f2bf(float f) {
    union { float f; unsigned u; } v; v.f = f;
    unsigned u = v.u;
    return (unsigned short)((u + 0x7fffu + ((u >> 16) & 1u)) >> 16);  // RNE
}

#define GLDS16(gp, lp)                                                          \
    __builtin_amdgcn_global_load_lds(                                           \
        (const __attribute__((address_space(1))) void*)(uintptr_t)(gp),         \
        (__attribute__((address_space(3))) void*)(uintptr_t)(lp), 16, 0, 0)

// ---------- elementwise cast fp32 -> bf16 (8 elems/thread) ----------
__global__ void cast_f32_to_bf16(const float* __restrict__ in,
                                 unsigned short* __restrict__ out, int n8) {
    int i = blockIdx.x * 256 + threadIdx.x;
    if (i >= n8) return;
    float4 a = ((const float4*)in)[2 * i];
    float4 b = ((const float4*)in)[2 * i + 1];
    ush8 o;
    o[0] = f2bf(a.x); o[1] = f2bf(a.y); o[2] = f2bf(a.z); o[3] = f2bf(a.w);
    o[4] = f2bf(b.x); o[5] = f2bf(b.y); o[6] = f2bf(b.z); o[7] = f2bf(b.w);
    ((ush8*)out)[i] = o;
}

// ---------- LDS-tiled transpose + cast: out[c][r] = bf16(in[r][c]) ----------
__global__ void transpose_cast(const float* __restrict__ in,
                               unsigned short* __restrict__ out, int R, int C) {
    __shared__ float t[32][33];
    int c0 = blockIdx.x * 32, r0 = blockIdx.y * 32;
    int x = threadIdx.x, y = threadIdx.y;  // block (32,8)
    #pragma unroll
    for (int i = 0; i < 32; i += 8) t[y + i][x] = in[(size_t)(r0 + y + i) * C + c0 + x];
    __syncthreads();
    #pragma unroll
    for (int i = 0; i < 32; i += 8)
        out[(size_t)(c0 + y + i) * R + r0 + x] = f2bf(t[x][y + i]);
}

// ---------- in-place interleaved RoPE on bf16 [tok][nh*64] ----------
__global__ void rope_inplace(unsigned short* __restrict__ X,
                             const int* __restrict__ pos_ids, int nh_log2) {
    int idx = blockIdx.x * 256 + threadIdx.x;
    int i   = idx & 31;                       // pair index (D/2 = 32)
    int tok = idx >> (5 + nh_log2);
    int pos = pos_ids[tok];
    // freq = 10000^(-2i/64) = exp2(-i * log2(10000)/32)
    float ang = (float)pos * exp2f(-0.41524101186092f * (float)i);
    float s = sinf(ang), c = cosf(ang);
    size_t base = ((size_t)idx >> 5 << 6) + 2 * i - ((size_t)(idx & 31) * 0); // tok*nh*64 + hh*64 + 2i
    base = (((size_t)idx >> 5) << 6) + 2 * i;   // (tok*nh + hh)*64 + 2i
    unsigned pr = *(const unsigned*)(X + base);
    float xr = bf2f((unsigned short)(pr & 0xffff));
    float xi = bf2f((unsigned short)(pr >> 16));
    float orr = xr * c - xi * s;
    float oi  = xr * s + xi * c;
    *(unsigned*)(X + base) = (unsigned)f2bf(orr) | ((unsigned)f2bf(oi) << 16);
}

// ---------- GEMM: C[M][N] = A[M][K] * Bt[N][K]^T  (bf16 in, fp32 acc) ----------
// 128x128 tile, BK=64, 256 threads (4 waves, 2x2 wave grid of 64x64),
// global_load_lds w16 staging with rule-21 swizzle (linear LDS dest,
// inverse-swizzled global src, swizzled ds_read).
template <int OUT_BF16>
__global__ __launch_bounds__(256) void gemm_bt(const unsigned short* __restrict__ A,
                                               const unsigned short* __restrict__ Bt,
                                               void* __restrict__ Cv, int N, int K) {
    __shared__ __align__(16) unsigned short As[128 * 64];
    __shared__ __align__(16) unsigned short Bs[128 * 64];
    const int t = threadIdx.x;
    const int lane = t & 63, w = t >> 6;
    const int wr = w >> 1, wc = w & 1;
    const int lr = lane & 15, lh = lane >> 4;
    const int m0 = blockIdx.y * 128, n0 = blockIdx.x * 128;

    f4v acc[4][4];
    #pragma unroll
    for (int i = 0; i < 4; ++i)
        #pragma unroll
        for (int j = 0; j < 4; ++j) acc[i][j] = f4v{0.f, 0.f, 0.f, 0.f};

    const int o_t = t * 16;
    for (int k0 = 0; k0 < K; k0 += 64) {
        __syncthreads();
        #pragma unroll
        for (int s = 0; s < 4; ++s) {
            int o = s * 4096 + o_t;          // linear LDS byte offset
            int row = o >> 7;
            int src = (o & 127) ^ ((row & 7) << 4);   // inverse-swizzled src col (bytes)
            const unsigned short* gA = A + (size_t)(m0 + row) * K + k0 + (src >> 1);
            GLDS16(gA, As + (o >> 1));
            const unsigned short* gB = Bt + (size_t)(n0 + row) * K + k0 + (src >> 1);
            GLDS16(gB, Bs + (o >> 1));
        }
        __syncthreads();
        #pragma unroll
        for (int kk = 0; kk < 2; ++kk) {
            bf8v af[4], bfr[4];
            #pragma unroll
            for (int mi = 0; mi < 4; ++mi) {
                int row = wr * 64 + mi * 16 + lr;
                int col = (kk * 32 + lh * 8) ^ ((row & 7) << 3);
                af[mi] = *(const bf8v*)(As + row * 64 + col);
            }
            #pragma unroll
            for (int ni = 0; ni < 4; ++ni) {
                int row = wc * 64 + ni * 16 + lr;
                int col = (kk * 32 + lh * 8) ^ ((row & 7) << 3);
                bfr[ni] = *(const bf8v*)(Bs + row * 64 + col);
            }
            #pragma unroll
            for (int mi = 0; mi < 4; ++mi)
                #pragma unroll
                for (int ni = 0; ni < 4; ++ni)
                    acc[mi][ni] = __builtin_amdgcn_mfma_f32_16x16x32_bf16(
                        af[mi], bfr[ni], acc[mi][ni], 0, 0, 0);
        }
    }
    #pragma unroll
    for (int mi = 0; mi < 4; ++mi)
        #pragma unroll
        for (int ni = 0; ni < 4; ++ni)
            #pragma unroll
            for (int r = 0; r < 4; ++r) {
                int row = m0 + wr * 64 + mi * 16 + lh * 4 + r;
                int col = n0 + wc * 64 + ni * 16 + lr;
                float v = acc[mi][ni][r];
                if (OUT_BF16) ((unsigned short*)Cv)[(size_t)row * N + col] = f2bf(v);
                else          ((float*)Cv)[(size_t)row * N + col] = v;
            }
}

// ---------- flash attention (causal, GQA 4:1), bf16 MFMA, fp32 softmax ----------
// block: 256 thr (4 waves), Q-tile 64 rows (16/wave), KV-tile 64, D=64.
__global__ __launch_bounds__(256) void flash_attn(const unsigned short* __restrict__ Q,
                                                  const unsigned short* __restrict__ Kg,
                                                  const unsigned short* __restrict__ Vg,
                                                  const int* __restrict__ amask,
                                                  unsigned short* __restrict__ O) {
    __shared__ __align__(16) unsigned short Ks[64 * 64];        // K[key][d], swizzled
    __shared__ __align__(16) unsigned short Vt[64 * 64];        // V^T[d][key], swizzled
    __shared__ __align__(16) unsigned short Ps[4][16 * 64];     // per-wave P[q][key], swizzled

    const int t = threadIdx.x, lane = t & 63, w = t >> 6;
    const int lr = lane & 15, lh = lane >> 4;
    const int qt = blockIdx.x, h = blockIdx.y, b = blockIdx.z;
    const int q0 = qt * 64;
    const size_t tok0 = (size_t)b * 2048;

    const unsigned short* Qp = Q + (tok0 + q0 + w * 16 + lr) * 2048 + h * 64;
    const unsigned short* Kb = Kg + tok0 * 512 + (h >> 2) * 64;
    const unsigned short* Vb = Vg + tok0 * 512 + (h >> 2) * 64;

    bf8v qa0 = *(const bf8v*)(Qp + lh * 8);
    bf8v qa1 = *(const bf8v*)(Qp + 32 + lh * 8);

    f4v oacc[4];
    #pragma unroll
    for (int i = 0; i < 4; ++i) oacc[i] = f4v{0.f, 0.f, 0.f, 0.f};
    float m_[4] = {-1e30f, -1e30f, -1e30f, -1e30f};
    float l_[4] = {0.f, 0.f, 0.f, 0.f};
    const int qrow_base = q0 + w * 16 + lh * 4;

    for (int kt = 0; kt <= qt; ++kt) {
        __syncthreads();
        // ---- stage K (row-major, swizzled) and V^T (double-XOR swizzle) ----
        #pragma unroll
        for (int s2 = 0; s2 < 2; ++s2) {
            int idx = s2 * 256 + t;
            int row = idx >> 3;           // key within tile
            int c8  = (idx & 7) * 8;      // dim start
            ush8 kv = *(const ush8*)(Kb + (size_t)(kt * 64 + row) * 512 + c8);
            *(ush8*)(Ks + row * 64 + (c8 ^ ((row & 7) << 3))) = kv;
            ush8 vv = *(const ush8*)(Vb + (size_t)(kt * 64 + row) * 512 + c8);
            #pragma unroll
            for (int j = 0; j < 8; ++j) {
                int d = c8 + j;
                int sw = ((d & 7) ^ ((d >> 3) & 7)) << 3;
                Vt[d * 64 + (row ^ sw)] = (unsigned short)vv[j];
            }
        }
        __syncthreads();

        // ---- S = Q K^T (C-layout: col=key=lr-frag, row=q=lh*4+r) ----
        f4v sa[4];
        #pragma unroll
        for (int kf = 0; kf < 4; ++kf) sa[kf] = f4v{0.f, 0.f, 0.f, 0.f};
        #pragma unroll
        for (int kk = 0; kk < 2; ++kk) {
            bf8v qa = kk ? qa1 : qa0;
            int col = kk * 32 + lh * 8;
            #pragma unroll
            for (int kf = 0; kf < 4; ++kf) {
                int key = kf * 16 + lr;
                bf8v kb = *(const bf8v*)(Ks + key * 64 + (col ^ ((key & 7) << 3)));
                sa[kf] = __builtin_amdgcn_mfma_f32_16x16x32_bf16(qa, kb, sa[kf], 0, 0, 0);
            }
        }

        // ---- mask + online softmax (fp32) ----
        float pv[4][4];
        float mx[4] = {-1e30f, -1e30f, -1e30f, -1e30f};
        #pragma unroll
        for (int kf = 0; kf < 4; ++kf) {
            int keyg = kt * 64 + kf * 16 + lr;
            int am = amask[b * 2048 + keyg];
            #pragma unroll
            for (int r = 0; r < 4; ++r) {
                float sv = sa[kf][r] * 0.125f;
                if (keyg > qrow_base + r || am == 0) sv = -1e30f;
                pv[r][kf] = sv;
                mx[r] = fmaxf(mx[r], sv);
            }
        }
        #pragma unroll
        for (int r = 0; r < 4; ++r) {
            float v = mx[r];
            v = fmaxf(v, __shfl_xor(v, 1));
            v = fmaxf(v, __shfl_xor(v, 2));
            v = fmaxf(v, __shfl_xor(v, 4));
            v = fmaxf(v, __shfl_xor(v, 8));
            mx[r] = v;
        }
        float fac[4], rs[4];
        #pragma unroll
        for (int r = 0; r < 4; ++r) {
            float mn = fmaxf(m_[r], mx[r]);
            fac[r] = expf(m_[r] - mn);
            m_[r] = mn;
            rs[r] = 0.f;
        }
        #pragma unroll
        for (int kf = 0; kf < 4; ++kf)
            #pragma unroll
            for (int r = 0; r < 4; ++r) {
                float p = expf(pv[r][kf] - m_[r]);
                pv[r][kf] = p;
                rs[r] += p;
            }
        #pragma unroll
        for (int r = 0; r < 4; ++r) {
            float v = rs[r];
            v += __shfl_xor(v, 1);
            v += __shfl_xor(v, 2);
            v += __shfl_xor(v, 4);
            v += __shfl_xor(v, 8);
            l_[r] = l_[r] * fac[r] + v;
        }
        #pragma unroll
        for (int df = 0; df < 4; ++df) {
            f4v o = oacc[df];
            o[0] *= fac[0]; o[1] *= fac[1]; o[2] *= fac[2]; o[3] *= fac[3];
            oacc[df] = o;
        }

        // ---- P -> wave-private LDS (bf16), then PV ----
        unsigned short* Pw = Ps[w];
        #pragma unroll
        for (int kf = 0; kf < 4; ++kf)
            #pragma unroll
            for (int r = 0; r < 4; ++r) {
                int ql = lh * 4 + r;
                int key = kf * 16 + lr;
                Pw[ql * 64 + (key ^ ((ql & 7) << 3))] = f2bf(pv[r][kf]);
            }
        #pragma unroll
        for (int kk = 0; kk < 2; ++kk) {
            int k0 = kk * 32 + lh * 8;
            bf8v pa = *(const bf8v*)(Pw + lr * 64 + (k0 ^ ((lr & 7) << 3)));
            #pragma unroll
            for (int df = 0; df < 4; ++df) {
                int d = df * 16 + lr;
                int sw = ((d & 7) ^ ((d >> 3) & 7)) << 3;
                bf8v vb = *(const bf8v*)(Vt + d * 64 + (k0 ^ sw));
                oacc[df] = __builtin_amdgcn_mfma_f32_16x16x32_bf16(pa, vb, oacc[df], 0, 0, 0);
            }
        }
    }

    // ---- epilogue: normalize, write bf16 [tok][H] ----
    #pragma unroll
    for (int df = 0; df < 4; ++df)
        #pragma unroll
        for (int r = 0; r < 4; ++r) {
            int qg = q0 + w * 16 + lh * 4 + r;
            float v = oacc[df][r] / l_[r];
            O[(tok0 + qg) * 2048 + h * 64 + df * 16 + lr] = f2bf(v);
        }
}

// ---------- launch ----------
extern "C" void kernel_launch(void* const* d_in, const int* in_sizes, int n_in,
                              void* d_out, int out_size, void* d_ws, size_t ws_size,
                              hipStream_t stream) {
    const float* hs   = (const float*)d_in[0];
    const int* amask  = (const int*)d_in[1];
    const int* pos    = (const int*)d_in[2];
    const float* wq   = (const float*)d_in[3];
    const float* wk   = (const float*)d_in[4];
    const float* wv   = (const float*)d_in[5];
    const float* wo   = (const float*)d_in[6];

    char* ws = (char*)d_ws;
    unsigned short* Xb  = (unsigned short*)(ws);              // 16,777,216 B
    unsigned short* Wqt = (unsigned short*)(ws + 16777216);   //  8,388,608
    unsigned short* Wkt = (unsigned short*)(ws + 25165824);   //  2,097,152
    unsigned short* Wvt = (unsigned short*)(ws + 27262976);   //  2,097,152
    unsigned short* Wot = (unsigned short*)(ws + 29360128);   //  8,388,608
    unsigned short* AOb = (unsigned short*)(ws + 37748736);   // 16,777,216 (ends 54,525,952)

    // Q/K/V bf16 scratch lives inside d_out (dead before final GEMM writes it)
    char* ob = (char*)d_out;
    unsigned short* Qb = (unsigned short*)ob;                 // 16,777,216
    unsigned short* Kb = (unsigned short*)(ob + 16777216);    //  4,194,304
    unsigned short* Vb = (unsigned short*)(ob + 20971520);    //  4,194,304 (ends 25,165,824)

    cast_f32_to_bf16<<<4096, 256, 0, stream>>>(hs, Xb, 1048576);
    transpose_cast<<<dim3(64, 64), dim3(32, 8), 0, stream>>>(wq, Wqt, 2048, 2048);
    transpose_cast<<<dim3(16, 64), dim3(32, 8), 0, stream>>>(wk, Wkt, 2048, 512);
    transpose_cast<<<dim3(16, 64), dim3(32, 8), 0, stream>>>(wv, Wvt, 2048, 512);
    transpose_cast<<<dim3(64, 64), dim3(32, 8), 0, stream>>>(wo, Wot, 2048, 2048);

    gemm_bt<1><<<dim3(16, 32), 256, 0, stream>>>(Xb, Wqt, (void*)Qb, 2048, 2048);
    gemm_bt<1><<<dim3(4, 32), 256, 0, stream>>>(Xb, Wkt, (void*)Kb, 512, 2048);
    gemm_bt<1><<<dim3(4, 32), 256, 0, stream>>>(Xb, Wvt, (void*)Vb, 512, 2048);

    rope_inplace<<<16384, 256, 0, stream>>>(Qb, pos, 5);  // NQ=32
    rope_inplace<<<4096, 256, 0, stream>>>(Kb, pos, 3);   // NKV=8

    flash_attn<<<dim3(32, 32, 2), 256, 0, stream>>>(Qb, Kb, Vb, amask, AOb);

    gemm_bt<0><<<dim3(16, 32), 256, 0, stream>>>(AOb, Wot, d_out, 2048, 2048);
}

// Round 2
// 330.982 us; speedup vs baseline: 1.5013x; 1.5013x over previous
//
#include <hip/hip_runtime.h>
#include <cstdint>

// ---------- types ----------
typedef __attribute__((ext_vector_type(8))) __bf16  bf8v;   // MFMA A/B operand (4 VGPRs)
typedef __attribute__((ext_vector_type(4))) float   f4v;    // MFMA C/D
typedef __attribute__((ext_vector_type(8))) unsigned short ush8; // 16B staging chunk

__device__ __forceinline__ float bf2f(unsigned short u) {
    union { unsigned u; float f; } v; v.u = ((unsigned)u) << 16; return v.f;
}
__device__ __forceinline__ unsigned short f2bf(float f) {
    union { float f; unsigned u; } v; v.f = f;
    unsigned u = v.u;
    return (unsigned short)((u + 0x7fffu + ((u >> 16) & 1u)) >> 16);  // RNE
}

#define GLDS16(gp, lp)                                                          \
    __builtin_amdgcn_global_load_lds(                                           \
        (const __attribute__((address_space(1))) void*)(uintptr_t)(gp),         \
        (__attribute__((address_space(3))) void*)(uintptr_t)(lp), 16, 0, 0)

// ---------- elementwise cast fp32 -> bf16 (8 elems/thread) ----------
__global__ void cast_f32_to_bf16(const float* __restrict__ in,
                                 unsigned short* __restrict__ out, int n8) {
    int i = blockIdx.x * 256 + threadIdx.x;
    if (i >= n8) return;
    float4 a = ((const float4*)in)[2 * i];
    float4 b = ((const float4*)in)[2 * i + 1];
    ush8 o;
    o[0] = f2bf(a.x); o[1] = f2bf(a.y); o[2] = f2bf(a.z); o[3] = f2bf(a.w);
    o[4] = f2bf(b.x); o[5] = f2bf(b.y); o[6] = f2bf(b.z); o[7] = f2bf(b.w);
    ((ush8*)out)[i] = o;
}

// ---------- LDS-tiled transpose + cast: out[c][r] = bf16(in[r][c]) ----------
__global__ void transpose_cast(const float* __restrict__ in,
                               unsigned short* __restrict__ out, int R, int C) {
    __shared__ float t[32][33];
    int c0 = blockIdx.x * 32, r0 = blockIdx.y * 32;
    int x = threadIdx.x, y = threadIdx.y;  // block (32,8)
    #pragma unroll
    for (int i = 0; i < 32; i += 8) t[y + i][x] = in[(size_t)(r0 + y + i) * C + c0 + x];
    __syncthreads();
    #pragma unroll
    for (int i = 0; i < 32; i += 8)
        out[(size_t)(c0 + y + i) * R + r0 + x] = f2bf(t[x][y + i]);
}

// ---------- in-place interleaved RoPE on bf16 [tok][nh*64] ----------
__global__ void rope_inplace(unsigned short* __restrict__ X,
                             const int* __restrict__ pos_ids, int nh_log2) {
    int idx = blockIdx.x * 256 + threadIdx.x;
    int i   = idx & 31;                       // pair index (D/2 = 32)
    int tok = idx >> (5 + nh_log2);
    int pos = pos_ids[tok];
    float ang = (float)pos * exp2f(-0.41524101186092f * (float)i);
    float s = sinf(ang), c = cosf(ang);
    size_t base = (((size_t)idx >> 5) << 6) + 2 * i;   // (tok*nh + hh)*64 + 2i
    unsigned pr = *(const unsigned*)(X + base);
    float xr = bf2f((unsigned short)(pr & 0xffff));
    float xi = bf2f((unsigned short)(pr >> 16));
    float orr = xr * c - xi * s;
    float oi  = xr * s + xi * c;
    *(unsigned*)(X + base) = (unsigned)f2bf(orr) | ((unsigned)f2bf(oi) << 16);
}

// ---------- GEMM: C[M][N] = A[M][K] * Bt[N][K]^T  (bf16 in, fp32 acc) ----------
template <int OUT_BF16>
__global__ __launch_bounds__(256) void gemm_bt(const unsigned short* __restrict__ A,
                                               const unsigned short* __restrict__ Bt,
                                               void* __restrict__ Cv, int N, int K) {
    __shared__ __align__(16) unsigned short As[128 * 64];
    __shared__ __align__(16) unsigned short Bs[128 * 64];
    const int t = threadIdx.x;
    const int lane = t & 63, w = t >> 6;
    const int wr = w >> 1, wc = w & 1;
    const int lr = lane & 15, lh = lane >> 4;
    const int m0 = blockIdx.y * 128, n0 = blockIdx.x * 128;

    f4v acc[4][4];
    #pragma unroll
    for (int i = 0; i < 4; ++i)
        #pragma unroll
        for (int j = 0; j < 4; ++j) acc[i][j] = f4v{0.f, 0.f, 0.f, 0.f};

    const int o_t = t * 16;
    for (int k0 = 0; k0 < K; k0 += 64) {
        __syncthreads();
        #pragma unroll
        for (int s = 0; s < 4; ++s) {
            int o = s * 4096 + o_t;          // linear LDS byte offset
            int row = o >> 7;
            int src = (o & 127) ^ ((row & 7) << 4);   // inverse-swizzled src col (bytes)
            const unsigned short* gA = A + (size_t)(m0 + row) * K + k0 + (src >> 1);
            GLDS16(gA, As + (o >> 1));
            const unsigned short* gB = Bt + (size_t)(n0 + row) * K + k0 + (src >> 1);
            GLDS16(gB, Bs + (o >> 1));
        }
        __syncthreads();
        #pragma unroll
        for (int kk = 0; kk < 2; ++kk) {
            bf8v af[4], bfr[4];
            #pragma unroll
            for (int mi = 0; mi < 4; ++mi) {
                int row = wr * 64 + mi * 16 + lr;
                int col = (kk * 32 + lh * 8) ^ ((row & 7) << 3);
                af[mi] = *(const bf8v*)(As + row * 64 + col);
            }
            #pragma unroll
            for (int ni = 0; ni < 4; ++ni) {
                int row = wc * 64 + ni * 16 + lr;
                int col = (kk * 32 + lh * 8) ^ ((row & 7) << 3);
                bfr[ni] = *(const bf8v*)(Bs + row * 64 + col);
            }
            #pragma unroll
            for (int mi = 0; mi < 4; ++mi)
                #pragma unroll
                for (int ni = 0; ni < 4; ++ni)
                    acc[mi][ni] = __builtin_amdgcn_mfma_f32_16x16x32_bf16(
                        af[mi], bfr[ni], acc[mi][ni], 0, 0, 0);
        }
    }
    #pragma unroll
    for (int mi = 0; mi < 4; ++mi)
        #pragma unroll
        for (int ni = 0; ni < 4; ++ni)
            #pragma unroll
            for (int r = 0; r < 4; ++r) {
                int row = m0 + wr * 64 + mi * 16 + lh * 4 + r;
                int col = n0 + wc * 64 + ni * 16 + lr;
                float v = acc[mi][ni][r];
                if (OUT_BF16) ((unsigned short*)Cv)[(size_t)row * N + col] = f2bf(v);
                else          ((float*)Cv)[(size_t)row * N + col] = v;
            }
}

// ---------- flash attention v2 ----------
// causal GQA 4:1, bf16 MFMA, fp32 exp2-domain softmax.
// Block: 256 thr (4 waves), Q-tile 64 rows (16/wave), KV-tile 64, D=64.
// Work-uniform pairing: block p does q-tiles {p, 31-p} -> 33 KV-iters each.
// K [tok][512] row-major; V pre-transposed in global: VtG[dg][tok].
// Double-buffered global_load_lds staging (issue next tile before computing
// current; one __syncthreads per tile drains vmcnt).
__global__ __launch_bounds__(256, 4) void flash_attn(
        const unsigned short* __restrict__ Q,
        const unsigned short* __restrict__ Kg,
        const unsigned short* __restrict__ VtG,
        const int* __restrict__ amask,
        unsigned short* __restrict__ O) {
    __shared__ __align__(16) unsigned short Ks[2][64 * 64];   // K[key][d], swizzled
    __shared__ __align__(16) unsigned short Vs[2][64 * 64];   // V^T[d][key], swizzled
    __shared__ __align__(16) unsigned short Ps[4][16 * 64];   // per-wave P[q][key], swizzled

    const int t = threadIdx.x, lane = t & 63, w = t >> 6;
    const int lr = lane & 15, lh = lane >> 4;
    const int pair = blockIdx.x, h = blockIdx.y, b = blockIdx.z;
    const size_t tok0 = (size_t)b * 2048;

    const unsigned short* Kb = Kg + tok0 * 512 + (h >> 2) * 64;             // rows=key
    const unsigned short* Vb = VtG + (size_t)((h >> 2) * 64) * 4096 + tok0; // rows=d
    const int* amrow = amask + b * 2048;

    // staging: chunk c = s*256+t (512 chunks of 16B per tile); row=c>>3, bytecol=(c&7)*16
#define STAGE(buf, kt)                                                            \
    {   _Pragma("unroll")                                                         \
        for (int s_ = 0; s_ < 2; ++s_) {                                          \
            int c_ = s_ * 256 + t;                                                \
            int row_ = c_ >> 3;                                                   \
            int sc_ = (((c_ & 7) * 16) ^ ((row_ & 7) << 4)) >> 1;                 \
            GLDS16(Kb + (size_t)((kt) * 64 + row_) * 512 + sc_, Ks[buf] + c_ * 8);\
            GLDS16(Vb + (size_t)row_ * 4096 + (kt) * 64 + sc_, Vs[buf] + c_ * 8); \
        }                                                                         \
    }

    const float SCL = 0.18033688011112042f;  // (1/sqrt(64)) * log2(e)
    int cur = 0;

    #pragma unroll 1
    for (int half = 0; half < 2; ++half) {
        const int qt = half ? (31 - pair) : pair;
        const int q0 = qt * 64;
        const int nkv = qt + 1;
        const int qrow_base = q0 + w * 16 + lh * 4;

        const unsigned short* Qp = Q + (tok0 + q0 + w * 16 + lr) * 2048 + h * 64;
        bf8v qa0 = *(const bf8v*)(Qp + lh * 8);
        bf8v qa1 = *(const bf8v*)(Qp + 32 + lh * 8);

        f4v oacc[4];
        #pragma unroll
        for (int i = 0; i < 4; ++i) oacc[i] = f4v{0.f, 0.f, 0.f, 0.f};
        float m_[4] = {-1e30f, -1e30f, -1e30f, -1e30f};
        float l_[4] = {0.f, 0.f, 0.f, 0.f};

        STAGE(cur, 0);
        __syncthreads();

        #pragma unroll 1
        for (int kt = 0; kt < nkv; ++kt) {
            // prefetch next KV tile into the other buffer (in flight during compute)
            if (kt + 1 < nkv) STAGE(cur ^ 1, kt + 1);

            int am[4];
            #pragma unroll
            for (int kf = 0; kf < 4; ++kf) am[kf] = amrow[kt * 64 + kf * 16 + lr];

            // ---- S = Q K^T ----
            f4v sa[4];
            #pragma unroll
            for (int kf = 0; kf < 4; ++kf) sa[kf] = f4v{0.f, 0.f, 0.f, 0.f};
            #pragma unroll
            for (int kk = 0; kk < 2; ++kk) {
                bf8v qa = kk ? qa1 : qa0;
                int col = kk * 32 + lh * 8;
                #pragma unroll
                for (int kf = 0; kf < 4; ++kf) {
                    int key = kf * 16 + lr;
                    bf8v kb = *(const bf8v*)(Ks[cur] + key * 64 + (col ^ ((key & 7) << 3)));
                    sa[kf] = __builtin_amdgcn_mfma_f32_16x16x32_bf16(qa, kb, sa[kf], 0, 0, 0);
                }
            }

            // ---- mask + online softmax (exp2 domain) ----
            const bool diag = (kt == qt);
            float pv[4][4];
            float mx[4] = {-1e30f, -1e30f, -1e30f, -1e30f};
            #pragma unroll
            for (int kf = 0; kf < 4; ++kf) {
                int keyg = kt * 64 + kf * 16 + lr;
                bool dead = (am[kf] == 0);
                #pragma unroll
                for (int r = 0; r < 4; ++r) {
                    float sv = sa[kf][r] * SCL;
                    if (dead || (diag && keyg > qrow_base + r)) sv = -1e30f;
                    pv[r][kf] = sv;
                    mx[r] = fmaxf(mx[r], sv);
                }
            }
            #pragma unroll
            for (int r = 0; r < 4; ++r) {
                float v = mx[r];
                v = fmaxf(v, __shfl_xor(v, 1));
                v = fmaxf(v, __shfl_xor(v, 2));
                v = fmaxf(v, __shfl_xor(v, 4));
                v = fmaxf(v, __shfl_xor(v, 8));
                mx[r] = v;
            }
            float fac[4], rs[4];
            #pragma unroll
            for (int r = 0; r < 4; ++r) {
                float mn = fmaxf(m_[r], mx[r]);
                fac[r] = exp2f(m_[r] - mn);
                m_[r] = mn;
                rs[r] = 0.f;
            }
            #pragma unroll
            for (int kf = 0; kf < 4; ++kf)
                #pragma unroll
                for (int r = 0; r < 4; ++r) {
                    float p = exp2f(pv[r][kf] - m_[r]);
                    pv[r][kf] = p;
                    rs[r] += p;
                }
            #pragma unroll
            for (int r = 0; r < 4; ++r) {
                float v = rs[r];
                v += __shfl_xor(v, 1);
                v += __shfl_xor(v, 2);
                v += __shfl_xor(v, 4);
                v += __shfl_xor(v, 8);
                l_[r] = l_[r] * fac[r] + v;
            }
            #pragma unroll
            for (int df = 0; df < 4; ++df) {
                f4v o = oacc[df];
                o[0] *= fac[0]; o[1] *= fac[1]; o[2] *= fac[2]; o[3] *= fac[3];
                oacc[df] = o;
            }

            // ---- P -> wave-private LDS (bf16), then PV ----
            unsigned short* Pw = Ps[w];
            #pragma unroll
            for (int kf = 0; kf < 4; ++kf)
                #pragma unroll
                for (int r = 0; r < 4; ++r) {
                    int ql = lh * 4 + r;
                    int key = kf * 16 + lr;
                    Pw[ql * 64 + (key ^ ((ql & 7) << 3))] = f2bf(pv[r][kf]);
                }
            #pragma unroll
            for (int kk = 0; kk < 2; ++kk) {
                int k0 = kk * 32 + lh * 8;
                bf8v pa = *(const bf8v*)(Pw + lr * 64 + (k0 ^ ((lr & 7) << 3)));
                #pragma unroll
                for (int df = 0; df < 4; ++df) {
                    int d = df * 16 + lr;
                    bf8v vb = *(const bf8v*)(Vs[cur] + d * 64 + (k0 ^ ((d & 7) << 3)));
                    oacc[df] = __builtin_amdgcn_mfma_f32_16x16x32_bf16(pa, vb, oacc[df], 0, 0, 0);
                }
            }

            __syncthreads();   // drains this iter's prefetch vmcnt + barrier
            cur ^= 1;
        }

        // ---- epilogue: normalize, write bf16 [tok][H] ----
        float inv[4];
        #pragma unroll
        for (int r = 0; r < 4; ++r) inv[r] = 1.0f / l_[r];
        #pragma unroll
        for (int df = 0; df < 4; ++df)
            #pragma unroll
            for (int r = 0; r < 4; ++r) {
                int qg = q0 + w * 16 + lh * 4 + r;
                float v = oacc[df][r] * inv[r];
                O[(tok0 + qg) * 2048 + h * 64 + df * 16 + lr] = f2bf(v);
            }
    }
#undef STAGE
}

// ---------- launch ----------
extern "C" void kernel_launch(void* const* d_in, const int* in_sizes, int n_in,
                              void* d_out, int out_size, void* d_ws, size_t ws_size,
                              hipStream_t stream) {
    const float* hs   = (const float*)d_in[0];
    const int* amask  = (const int*)d_in[1];
    const int* pos    = (const int*)d_in[2];
    const float* wq   = (const float*)d_in[3];
    const float* wk   = (const float*)d_in[4];
    const float* wv   = (const float*)d_in[5];
    const float* wo   = (const float*)d_in[6];

    char* ws = (char*)d_ws;
    unsigned short* Xb  = (unsigned short*)(ws);              // 16,777,216 B
    unsigned short* Wqt = (unsigned short*)(ws + 16777216);   //  8,388,608
    unsigned short* Wkt = (unsigned short*)(ws + 25165824);   //  2,097,152
    unsigned short* Wvt = (unsigned short*)(ws + 27262976);   //  2,097,152
    unsigned short* Wot = (unsigned short*)(ws + 29360128);   //  8,388,608
    unsigned short* AOb = (unsigned short*)(ws + 37748736);   // 16,777,216 (ends 54,525,952)

    // Q/K/V^T bf16 scratch lives inside d_out (dead before final GEMM writes it)
    char* ob = (char*)d_out;
    unsigned short* Qb  = (unsigned short*)ob;                // 16,777,216
    unsigned short* Kb  = (unsigned short*)(ob + 16777216);   //  4,194,304
    unsigned short* VtG = (unsigned short*)(ob + 20971520);   //  4,194,304 (ends 25,165,824)

    cast_f32_to_bf16<<<4096, 256, 0, stream>>>(hs, Xb, 1048576);
    transpose_cast<<<dim3(64, 64), dim3(32, 8), 0, stream>>>(wq, Wqt, 2048, 2048);
    transpose_cast<<<dim3(16, 64), dim3(32, 8), 0, stream>>>(wk, Wkt, 2048, 512);
    transpose_cast<<<dim3(16, 64), dim3(32, 8), 0, stream>>>(wv, Wvt, 2048, 512);
    transpose_cast<<<dim3(64, 64), dim3(32, 8), 0, stream>>>(wo, Wot, 2048, 2048);

    gemm_bt<1><<<dim3(16, 32), 256, 0, stream>>>(Xb, Wqt, (void*)Qb, 2048, 2048);
    gemm_bt<1><<<dim3(4, 32), 256, 0, stream>>>(Xb, Wkt, (void*)Kb, 512, 2048);
    // V^T directly: C[dg][tok] = sum_k Wvt[dg][k] * Xb[tok][k]
    gemm_bt<1><<<dim3(32, 4), 256, 0, stream>>>(Wvt, Xb, (void*)VtG, 4096, 2048);

    rope_inplace<<<16384, 256, 0, stream>>>(Qb, pos, 5);  // NQ=32
    rope_inplace<<<4096, 256, 0, stream>>>(Kb, pos, 3);   // NKV=8

    flash_attn<<<dim3(16, 32, 2), 256, 0, stream>>>(Qb, Kb, VtG, amask, AOb);

    gemm_bt<0><<<dim3(16, 32), 256, 0, stream>>>(AOb, Wot, d_out, 2048, 2048);
}

// Round 3
// 233.320 us; speedup vs baseline: 2.1297x; 1.4186x over previous
//
#include <hip/hip_runtime.h>
#include <cstdint>

// ---------- types ----------
typedef __attribute__((ext_vector_type(8))) __bf16  bf8v;   // MFMA A/B operand (4 VGPRs)
typedef __attribute__((ext_vector_type(4))) float   f4v;    // MFMA C/D
typedef __attribute__((ext_vector_type(8))) unsigned short ush8; // 16B staging chunk

__device__ __forceinline__ float bf2f(unsigned short u) {
    union { unsigned u; float f; } v; v.u = ((unsigned)u) << 16; return v.f;
}
__device__ __forceinline__ unsigned short f2bf(float f) {
    union { float f; unsigned u; } v; v.f = f;
    unsigned u = v.u;
    return (unsigned short)((u + 0x7fffu + ((u >> 16) & 1u)) >> 16);  // RNE
}
// native HW converts (RNE) — compiler emits v_cvt(_pk)_bf16_f32
__device__ __forceinline__ unsigned short f2bf_n(float f) {
    union { __bf16 h; unsigned short s; } v; v.h = (__bf16)f; return v.s;
}
__device__ __forceinline__ unsigned pack2bf(float a, float b) {
    union { __bf16 h[2]; unsigned u; } v;
    v.h[0] = (__bf16)a; v.h[1] = (__bf16)b; return v.u;
}

#define GLDS16(gp, lp)                                                          \
    __builtin_amdgcn_global_load_lds(                                           \
        (const __attribute__((address_space(1))) void*)(uintptr_t)(gp),         \
        (__attribute__((address_space(3))) void*)(uintptr_t)(lp), 16, 0, 0)

// ---------- elementwise cast fp32 -> bf16 (8 elems/thread) ----------
__global__ void cast_f32_to_bf16(const float* __restrict__ in,
                                 unsigned short* __restrict__ out, int n8) {
    int i = blockIdx.x * 256 + threadIdx.x;
    if (i >= n8) return;
    float4 a = ((const float4*)in)[2 * i];
    float4 b = ((const float4*)in)[2 * i + 1];
    ush8 o;
    o[0] = f2bf(a.x); o[1] = f2bf(a.y); o[2] = f2bf(a.z); o[3] = f2bf(a.w);
    o[4] = f2bf(b.x); o[5] = f2bf(b.y); o[6] = f2bf(b.z); o[7] = f2bf(b.w);
    ((ush8*)out)[i] = o;
}

// ---------- LDS-tiled transpose + cast: out[c][r] = bf16(in[r][c]) ----------
__global__ void transpose_cast(const float* __restrict__ in,
                               unsigned short* __restrict__ out, int R, int C) {
    __shared__ float t[32][33];
    int c0 = blockIdx.x * 32, r0 = blockIdx.y * 32;
    int x = threadIdx.x, y = threadIdx.y;  // block (32,8)
    #pragma unroll
    for (int i = 0; i < 32; i += 8) t[y + i][x] = in[(size_t)(r0 + y + i) * C + c0 + x];
    __syncthreads();
    #pragma unroll
    for (int i = 0; i < 32; i += 8)
        out[(size_t)(c0 + y + i) * R + r0 + x] = f2bf(t[x][y + i]);
}

// ---------- bf16 transpose of V block: in [4096][3072]@col2560 -> out [512][4096] ----------
__global__ void transpose_v_bf16(const unsigned short* __restrict__ in,
                                 unsigned short* __restrict__ out) {
    __shared__ unsigned short t[32][33];
    int c0 = blockIdx.x * 32;   // v-col (0..511)
    int r0 = blockIdx.y * 32;   // token
    int x = threadIdx.x, y = threadIdx.y;  // block (32,8)
    #pragma unroll
    for (int i = 0; i < 32; i += 8)
        t[y + i][x] = in[(size_t)(r0 + y + i) * 3072 + 2560 + c0 + x];
    __syncthreads();
    #pragma unroll
    for (int i = 0; i < 32; i += 8)
        out[(size_t)(c0 + y + i) * 4096 + r0 + x] = t[x][y + i];
}

// ---------- in-place interleaved RoPE on bf16, strided rows ----------
__global__ void rope_strided(unsigned short* __restrict__ X,
                             const int* __restrict__ pos_ids,
                             int coloff, int stride, int nh_log2) {
    int idx = blockIdx.x * 256 + threadIdx.x;
    int i   = idx & 31;                       // pair index (D/2 = 32)
    int hh  = (idx >> 5) & ((1 << nh_log2) - 1);
    int tok = idx >> (5 + nh_log2);
    int pos = pos_ids[tok];
    float ang = (float)pos * exp2f(-0.41524101186092f * (float)i);
    float s = sinf(ang), c = cosf(ang);
    unsigned short* p = X + (size_t)tok * stride + coloff + hh * 64 + 2 * i;
    unsigned pr = *(const unsigned*)p;
    float xr = bf2f((unsigned short)(pr & 0xffff));
    float xi = bf2f((unsigned short)(pr >> 16));
    float orr = xr * c - xi * s;
    float oi  = xr * s + xi * c;
    *(unsigned*)p = (unsigned)f2bf(orr) | ((unsigned)f2bf(oi) << 16);
}

// ---------- GEMM: C[M][N] = A[M][K] * Bt[N][K]^T  (bf16 in, fp32 acc) ----------
template <int OUT_BF16>
__global__ __launch_bounds__(256) void gemm_bt(const unsigned short* __restrict__ A,
                                               const unsigned short* __restrict__ Bt,
                                               void* __restrict__ Cv, int N, int K) {
    __shared__ __align__(16) unsigned short As[128 * 64];
    __shared__ __align__(16) unsigned short Bs[128 * 64];
    const int t = threadIdx.x;
    const int lane = t & 63, w = t >> 6;
    const int wr = w >> 1, wc = w & 1;
    const int lr = lane & 15, lh = lane >> 4;
    const int m0 = blockIdx.y * 128, n0 = blockIdx.x * 128;

    f4v acc[4][4];
    #pragma unroll
    for (int i = 0; i < 4; ++i)
        #pragma unroll
        for (int j = 0; j < 4; ++j) acc[i][j] = f4v{0.f, 0.f, 0.f, 0.f};

    const int o_t = t * 16;
    for (int k0 = 0; k0 < K; k0 += 64) {
        __syncthreads();
        #pragma unroll
        for (int s = 0; s < 4; ++s) {
            int o = s * 4096 + o_t;          // linear LDS byte offset
            int row = o >> 7;
            int src = (o & 127) ^ ((row & 7) << 4);   // inverse-swizzled src col (bytes)
            const unsigned short* gA = A + (size_t)(m0 + row) * K + k0 + (src >> 1);
            GLDS16(gA, As + (o >> 1));
            const unsigned short* gB = Bt + (size_t)(n0 + row) * K + k0 + (src >> 1);
            GLDS16(gB, Bs + (o >> 1));
        }
        __syncthreads();
        #pragma unroll
        for (int kk = 0; kk < 2; ++kk) {
            bf8v af[4], bfr[4];
            #pragma unroll
            for (int mi = 0; mi < 4; ++mi) {
                int row = wr * 64 + mi * 16 + lr;
                int col = (kk * 32 + lh * 8) ^ ((row & 7) << 3);
                af[mi] = *(const bf8v*)(As + row * 64 + col);
            }
            #pragma unroll
            for (int ni = 0; ni < 4; ++ni) {
                int row = wc * 64 + ni * 16 + lr;
                int col = (kk * 32 + lh * 8) ^ ((row & 7) << 3);
                bfr[ni] = *(const bf8v*)(Bs + row * 64 + col);
            }
            #pragma unroll
            for (int mi = 0; mi < 4; ++mi)
                #pragma unroll
                for (int ni = 0; ni < 4; ++ni)
                    acc[mi][ni] = __builtin_amdgcn_mfma_f32_16x16x32_bf16(
                        af[mi], bfr[ni], acc[mi][ni], 0, 0, 0);
        }
    }
    #pragma unroll
    for (int mi = 0; mi < 4; ++mi)
        #pragma unroll
        for (int ni = 0; ni < 4; ++ni)
            #pragma unroll
            for (int r = 0; r < 4; ++r) {
                int row = m0 + wr * 64 + mi * 16 + lh * 4 + r;
                int col = n0 + wc * 64 + ni * 16 + lr;
                float v = acc[mi][ni][r];
                if (OUT_BF16) ((unsigned short*)Cv)[(size_t)row * N + col] = f2bf(v);
                else          ((float*)Cv)[(size_t)row * N + col] = v;
            }
}

// ---------- flash attention v3: operand-swapped QK^T, lane-local softmax ----------
// causal GQA 4:1, bf16 MFMA, fp32 exp2-domain softmax.
// Block: 256 thr (4 waves), Q-tile 64 rows (16/wave), KV-tile 64, D=64.
// Work-uniform pairing: block p does q-tiles {p, 31-p} -> 33 KV-iters.
// S^T = mfma(K, Q): lane holds one q-row (q = lane&15), 16 keys -> in-lane
// row reduce + shfl_xor(16/32); P packs in-lane (4 consecutive keys) ->
// 4 x ds_write_b64; PV reads P as A-frag (row = lane&15 = q) unchanged.
__global__ __launch_bounds__(256, 4) void flash_attn(
        const unsigned short* __restrict__ QKV,   // [4096][3072] (Q|K|V cols)
        const unsigned short* __restrict__ VtG,   // [512][4096]
        const int* __restrict__ amask,
        unsigned short* __restrict__ O) {         // [4096][2048]
    __shared__ __align__(16) unsigned short Ks[2][64 * 64];   // K[key][d], swizzled
    __shared__ __align__(16) unsigned short Vs[2][64 * 64];   // V^T[d][key], swizzled
    __shared__ __align__(16) unsigned short Ps[4][16 * 64];   // per-wave P[q][key], swizzled

    const int t = threadIdx.x, lane = t & 63, w = t >> 6;
    const int lr = lane & 15, lh = lane >> 4;
    const int pair = blockIdx.x, h = blockIdx.y, b = blockIdx.z;
    const size_t tok0 = (size_t)b * 2048;

    const unsigned short* Kb = QKV + tok0 * 3072 + 2048 + (h >> 2) * 64;    // row stride 3072
    const unsigned short* Vb = VtG + (size_t)((h >> 2) * 64) * 4096 + tok0; // row stride 4096
    const int* amrow = amask + b * 2048;

#define STAGE(buf, kt)                                                              \
    {   _Pragma("unroll")                                                           \
        for (int s_ = 0; s_ < 2; ++s_) {                                            \
            int c_ = s_ * 256 + t;                                                  \
            int row_ = c_ >> 3;                                                     \
            int sc_ = (((c_ & 7) * 16) ^ ((row_ & 7) << 4)) >> 1;                   \
            GLDS16(Kb + (size_t)((kt) * 64 + row_) * 3072 + sc_, Ks[buf] + c_ * 8); \
            GLDS16(Vb + (size_t)row_ * 4096 + (kt) * 64 + sc_, Vs[buf] + c_ * 8);   \
        }                                                                           \
    }

    const float SCL = 0.18033688011112042f;  // (1/sqrt(64)) * log2(e)
    int cur = 0;

    #pragma unroll 1
    for (int half = 0; half < 2; ++half) {
        const int qt = half ? (31 - pair) : pair;
        const int q0 = qt * 64;
        const int nkv = qt + 1;
        const int qloc = w * 16 + lr;   // this lane's q row within the 64-row tile

        const unsigned short* Qp = QKV + (tok0 + q0 + qloc) * 3072 + h * 64;
        bf8v qa0 = *(const bf8v*)(Qp + lh * 8);
        bf8v qa1 = *(const bf8v*)(Qp + 32 + lh * 8);

        f4v oacc[4];
        #pragma unroll
        for (int i = 0; i < 4; ++i) oacc[i] = f4v{0.f, 0.f, 0.f, 0.f};
        float m_ = -1e30f, l_ = 0.f;

        STAGE(cur, 0);
        __syncthreads();

        #pragma unroll 1
        for (int kt = 0; kt < nkv; ++kt) {
            if (kt + 1 < nkv) STAGE(cur ^ 1, kt + 1);

            int amv[4][4];
            #pragma unroll
            for (int kf = 0; kf < 4; ++kf) {
                int4 aq = *(const int4*)(amrow + kt * 64 + kf * 16 + lh * 4);
                amv[kf][0] = aq.x; amv[kf][1] = aq.y; amv[kf][2] = aq.z; amv[kf][3] = aq.w;
            }

            // ---- S^T = K Q^T : C row = key = lh*4+r (+16kf), col = q = lr ----
            f4v sa[4];
            #pragma unroll
            for (int kf = 0; kf < 4; ++kf) sa[kf] = f4v{0.f, 0.f, 0.f, 0.f};
            #pragma unroll
            for (int kk = 0; kk < 2; ++kk) {
                bf8v qa = kk ? qa1 : qa0;
                int col = kk * 32 + lh * 8;
                #pragma unroll
                for (int kf = 0; kf < 4; ++kf) {
                    bf8v kb = *(const bf8v*)(Ks[cur] + (kf * 16 + lr) * 64 + (col ^ ((lr & 7) << 3)));
                    sa[kf] = __builtin_amdgcn_mfma_f32_16x16x32_bf16(kb, qa, sa[kf], 0, 0, 0);
                }
            }

            // ---- mask (fast path when tile fully alive & off-diagonal) ----
            const bool diag = (kt == qt);
            int av = amv[0][0];
            #pragma unroll
            for (int kf = 0; kf < 4; ++kf)
                #pragma unroll
                for (int r = 0; r < 4; ++r) av &= amv[kf][r];
            const bool allAlive = __all(av != 0);

            float pvv[4][4];   // [kf][r] raw scores for key = kf*16+lh*4+r, row q=lr
            if (allAlive && !diag) {
                #pragma unroll
                for (int kf = 0; kf < 4; ++kf)
                    #pragma unroll
                    for (int r = 0; r < 4; ++r) pvv[kf][r] = sa[kf][r];
            } else {
                #pragma unroll
                for (int kf = 0; kf < 4; ++kf)
                    #pragma unroll
                    for (int r = 0; r < 4; ++r) {
                        int keyl = kf * 16 + lh * 4 + r;
                        bool dead = (amv[kf][r] == 0) || (diag && keyl > qloc);
                        pvv[kf][r] = dead ? -1e30f : sa[kf][r];
                    }
            }

            // ---- lane-local online softmax (row q = lr lives in this lane) ----
            float t0 = fmaxf(fmaxf(pvv[0][0], pvv[0][1]), fmaxf(pvv[0][2], pvv[0][3]));
            float t1 = fmaxf(fmaxf(pvv[1][0], pvv[1][1]), fmaxf(pvv[1][2], pvv[1][3]));
            float t2 = fmaxf(fmaxf(pvv[2][0], pvv[2][1]), fmaxf(pvv[2][2], pvv[2][3]));
            float t3 = fmaxf(fmaxf(pvv[3][0], pvv[3][1]), fmaxf(pvv[3][2], pvv[3][3]));
            float mx = fmaxf(fmaxf(t0, t1), fmaxf(t2, t3));
            mx = fmaxf(mx, __shfl_xor(mx, 16));
            mx = fmaxf(mx, __shfl_xor(mx, 32));

            float mn = fmaxf(m_, mx * SCL);
            float fac = exp2f(m_ - mn);
            m_ = mn;

            float pe[4][4];
            #pragma unroll
            for (int kf = 0; kf < 4; ++kf)
                #pragma unroll
                for (int r = 0; r < 4; ++r)
                    pe[kf][r] = exp2f(fmaf(pvv[kf][r], SCL, -mn));
            float s0 = (pe[0][0] + pe[0][1]) + (pe[0][2] + pe[0][3]);
            float s1 = (pe[1][0] + pe[1][1]) + (pe[1][2] + pe[1][3]);
            float s2 = (pe[2][0] + pe[2][1]) + (pe[2][2] + pe[2][3]);
            float s3 = (pe[3][0] + pe[3][1]) + (pe[3][2] + pe[3][3]);
            float rs = (s0 + s1) + (s2 + s3);
            rs += __shfl_xor(rs, 16);
            rs += __shfl_xor(rs, 32);
            l_ = l_ * fac + rs;

            // redistribute fac to accumulator rows (row = lh*4+r within wave)
            float facr[4];
            #pragma unroll
            for (int r = 0; r < 4; ++r) facr[r] = __shfl(fac, lh * 4 + r);
            #pragma unroll
            for (int df = 0; df < 4; ++df) {
                f4v o = oacc[df];
                o[0] *= facr[0]; o[1] *= facr[1]; o[2] *= facr[2]; o[3] *= facr[3];
                oacc[df] = o;
            }

            // ---- P -> wave-private LDS: pack pairs in-lane, 4 x b64 writes ----
            unsigned short* Pw = Ps[w];
            #pragma unroll
            for (int kf = 0; kf < 4; ++kf) {
                uint2 pk;
                pk.x = pack2bf(pe[kf][0], pe[kf][1]);
                pk.y = pack2bf(pe[kf][2], pe[kf][3]);
                int idx = lr * 64 + ((kf * 16 + lh * 4) ^ ((lr & 7) << 3));
                *(uint2*)(Pw + idx) = pk;
            }

            // ---- PV: O[q][d] += P[q][k] V[k][d] ----
            #pragma unroll
            for (int kk = 0; kk < 2; ++kk) {
                int k0c = kk * 32 + lh * 8;
                bf8v pa = *(const bf8v*)(Pw + lr * 64 + (k0c ^ ((lr & 7) << 3)));
                #pragma unroll
                for (int df = 0; df < 4; ++df) {
                    int d = df * 16 + lr;
                    bf8v vb = *(const bf8v*)(Vs[cur] + d * 64 + (k0c ^ ((d & 7) << 3)));
                    oacc[df] = __builtin_amdgcn_mfma_f32_16x16x32_bf16(pa, vb, oacc[df], 0, 0, 0);
                }
            }

            __syncthreads();   // drains this iter's prefetch vmcnt + barrier
            cur ^= 1;
        }

        // ---- epilogue: normalize, write bf16 [tok][2048] ----
        float invl = 1.0f / l_;
        float invr[4];
        #pragma unroll
        for (int r = 0; r < 4; ++r) invr[r] = __shfl(invl, lh * 4 + r);
        #pragma unroll
        for (int df = 0; df < 4; ++df)
            #pragma unroll
            for (int r = 0; r < 4; ++r) {
                int qg = q0 + w * 16 + lh * 4 + r;
                float v = oacc[df][r] * invr[r];
                O[(tok0 + qg) * 2048 + h * 64 + df * 16 + lr] = f2bf_n(v);
            }
    }
#undef STAGE
}

// ---------- launch ----------
extern "C" void kernel_launch(void* const* d_in, const int* in_sizes, int n_in,
                              void* d_out, int out_size, void* d_ws, size_t ws_size,
                              hipStream_t stream) {
    const float* hs   = (const float*)d_in[0];
    const int* amask  = (const int*)d_in[1];
    const int* pos    = (const int*)d_in[2];
    const float* wq   = (const float*)d_in[3];
    const float* wk   = (const float*)d_in[4];
    const float* wv   = (const float*)d_in[5];
    const float* wo   = (const float*)d_in[6];

    char* ws = (char*)d_ws;
    unsigned short* Xb   = (unsigned short*)(ws);             // 16,777,216 B
    unsigned short* Wqkv = (unsigned short*)(ws + 16777216);  // 12,582,912  [3072][2048]
    unsigned short* Wot  = (unsigned short*)(ws + 29360128);  //  8,388,608
    unsigned short* AOb  = (unsigned short*)(ws + 37748736);  // 16,777,216 (ends 54,525,952)

    // QKV bf16 [4096][3072] + VtG [512][4096] live inside d_out (dead before final GEMM)
    char* ob = (char*)d_out;
    unsigned short* QKV = (unsigned short*)ob;                // 25,165,824
    unsigned short* VtG = (unsigned short*)(ob + 25165824);   //  4,194,304 (ends 29,360,128)

    cast_f32_to_bf16<<<4096, 256, 0, stream>>>(hs, Xb, 1048576);
    // W^T blocks laid out contiguously: rows 0..2047 = Wq^T, 2048..2559 = Wk^T, 2560..3071 = Wv^T
    transpose_cast<<<dim3(64, 64), dim3(32, 8), 0, stream>>>(wq, Wqkv, 2048, 2048);
    transpose_cast<<<dim3(16, 64), dim3(32, 8), 0, stream>>>(wk, Wqkv + 4194304, 2048, 512);
    transpose_cast<<<dim3(16, 64), dim3(32, 8), 0, stream>>>(wv, Wqkv + 5242880, 2048, 512);
    transpose_cast<<<dim3(64, 64), dim3(32, 8), 0, stream>>>(wo, Wot, 2048, 2048);

    // fused QKV projection: [4096][3072]
    gemm_bt<1><<<dim3(24, 32), 256, 0, stream>>>(Xb, Wqkv, (void*)QKV, 3072, 2048);

    rope_strided<<<16384, 256, 0, stream>>>(QKV, pos, 0, 3072, 5);     // Q: 32 heads
    rope_strided<<<4096, 256, 0, stream>>>(QKV, pos, 2048, 3072, 3);   // K: 8 heads

    transpose_v_bf16<<<dim3(16, 128), dim3(32, 8), 0, stream>>>(QKV, VtG);

    flash_attn<<<dim3(16, 32, 2), 256, 0, stream>>>(QKV, VtG, amask, AOb);

    gemm_bt<0><<<dim3(16, 32), 256, 0, stream>>>(AOb, Wot, d_out, 2048, 2048);
}